// Round 4
// baseline (325.127 us; speedup 1.0000x reference)
//
#include <hip/hip_runtime.h>

typedef unsigned short u16;
typedef unsigned int u32;
typedef _Float16 half8 __attribute__((ext_vector_type(8)));
typedef __fp16 fp16x2 __attribute__((ext_vector_type(2)));
typedef float f32x16 __attribute__((ext_vector_type(16)));

union HU { uint4 u; half8 h; };
union PK { fp16x2 h; u32 u; };

__device__ __forceinline__ u16 f2h(float f) {
  union { _Float16 h; u16 u; } c;
  c.h = (_Float16)f;
  return c.u;
}

// async global->LDS DMA, 16 B per lane (lds dest = wave-uniform base + lane*16)
typedef const __attribute__((address_space(1))) u32 gu32;
typedef __attribute__((address_space(3))) u32 lu32;
__device__ __forceinline__ void gload_lds16(const void* g, void* l) {
  __builtin_amdgcn_global_load_lds((gu32*)g, (lu32*)l, 16, 0, 0);
}

// Pack weights (O=64, I=64, 3, 3) fp32 -> fp16 in exact A-fragment order:
// wbuf[((t*2 + mt)*64 + lane)*8 + j] = w[m][c][rs]
//   m = mt*32 + (lane&31), k = t*16 + (lane>>5)*8 + j, rs = k>>6, c = k&63
// K ordering: k = rs*64 + c (rs-major, c-minor); ktile t = rs*4 + cq.
__global__ void prep_w(const float* __restrict__ w, u16* __restrict__ wbuf) {
  int idx = blockIdx.x * 256 + threadIdx.x;  // 36864 total
  int j    = idx & 7;
  int lane = (idx >> 3) & 63;
  int mt   = (idx >> 9) & 1;
  int t    = idx >> 10;
  int m  = mt * 32 + (lane & 31);
  int k  = t * 16 + (lane >> 5) * 8 + j;
  int rs = k >> 6;
  int c  = k & 63;
  wbuf[idx] = f2h(w[(m * 64 + c) * 9 + rs]);
}

// Implicit-GEMM conv: M = O = 64, N = pixels, K = 576 in 4 quarters of 16 ch.
// v4: software-pipelined phases (v3 was serial: stage -> barrier -> K-loop).
// Per phase cq:
//   (1) ds_read this quarter's 9 A-frags wlds -> regs (frees wlds)
//   (2) __syncthreads  [all waves own their A; wlds reusable]
//   (3) issue async w-DMA (global_load_lds) for quarter cq+1 -> wlds
//   (4) issue x global loads for quarter cq+1 -> 16 regs (issue-early)
//   (5) K-loop: 9 x {ds_read B from xlds[cur]; MFMA(A-reg, B)} — pure LDS+MFMA
//   (6) drain x loads, pkrtz, ds_write -> xlds[cur^1] (write-late)
//   (7) __syncthreads  [drains DMA + x writes for next phase]
// All global latency (w-DMA + x loads) hides under the K-loop.
// LDS: xlds dbuf 2 x 6*130*8 fp16 = 24,960 B + wlds 18*512 fp16 = 18,432 B
//   -> 43.4 KB -> 3 blocks/CU; launch_bounds(512,6) caps regs at 85
//   (acc 16 + A 36 + x-in-flight 16 + addressing ~15).
// Halo-padded pixel axis (slots 0/129 zeroed once per buffer): no bounds logic.
// All LDS ops are lane-contiguous 16 B -> conflict-free.
__global__ __launch_bounds__(512, 6) void conv_mfma(
    const float* __restrict__ x, const u16* __restrict__ wbuf,
    const float* __restrict__ bias, float* __restrict__ out) {
  __shared__ u16 xlds[2][6 * 130 * 8];  // [buf][slab 6 = row3 x cblk2][px-slot 130][ch 8]
  __shared__ u16 wlds[18 * 512];        // [frag 18 = rs9 x mt2][512]

  int tid = threadIdx.x;
  int lane = tid & 63;
  int wave = tid >> 6;  // 0..7
  int bid = blockIdx.x;
  int wg = ((bid & 7) << 9) | (bid >> 3);  // bijective XCD-contiguous remap
  int nb = wg >> 7;    // batch [0,32)
  int h  = wg & 127;   // output row [0,128)

  int l31 = lane & 31;
  int half = lane >> 5;
  int mt = wave >> 2;  // this wave's mtile
  int nq = wave & 3;   // this wave's 32-pixel ntile

  // zero halo slots (0 and 129) of all 6 slabs in BOTH buffers, once.
  if (tid < 12) {
    int b = tid / 6, sl = tid % 6;
    *(uint4*)&xlds[b][(sl * 130 + 0) * 8]   = make_uint4(0u, 0u, 0u, 0u);
    *(uint4*)&xlds[b][(sl * 130 + 129) * 8] = make_uint4(0u, 0u, 0u, 0u);
  }

  // ---- prologue: stage x(quarter 0) -> xlds[0] synchronously ----
#pragma unroll
  for (int s = 0; s < 2; ++s) {
    int id = s * 8 + wave;  // 12 tasks = (row3, cblk2, w-half2)
    if (id < 12) {
      int row = id >> 2, cblk = (id >> 1) & 1, w2 = id & 1;
      int hin = h - 1 + row;
      const float* base = x + (((size_t)(nb * 64 + cblk * 8) * 128 + hin) * 128);
      int w = w2 * 64 + lane;
      uint4 v = make_uint4(0u, 0u, 0u, 0u);
      if (hin >= 0 && hin < 128) {
        float f[8];
#pragma unroll
        for (int j = 0; j < 8; ++j) f[j] = base[(size_t)j * 16384 + w];
        PK p0, p1, p2, p3;
        p0.h = __builtin_amdgcn_cvt_pkrtz(f[0], f[1]);
        p1.h = __builtin_amdgcn_cvt_pkrtz(f[2], f[3]);
        p2.h = __builtin_amdgcn_cvt_pkrtz(f[4], f[5]);
        p3.h = __builtin_amdgcn_cvt_pkrtz(f[6], f[7]);
        v = make_uint4(p0.u, p1.u, p2.u, p3.u);
      }
      *(uint4*)&xlds[0][((row * 2 + cblk) * 130 + 1 + w) * 8] = v;
    }
  }
  // ---- prologue: async DMA w(quarter 0) -> wlds ----
  // 18 frags x 1 KB; frag f = rs*2+fmt holds wbuf frag gf = rs*8 + cq*2 + fmt.
#pragma unroll
  for (int s = 0; s < 3; ++s) {
    int f = s * 8 + wave;
    if (f < 18) {
      int gf = (f >> 1) * 8 + (f & 1);  // cq = 0
      gload_lds16(&wbuf[(gf * 64 + lane) * 8], &wlds[f * 512]);
    }
  }
  __syncthreads();  // drains x writes + w-DMA

  f32x16 acc = {};

#pragma unroll
  for (int cq = 0; cq < 4; ++cq) {
    const int cur = cq & 1;

    // (1) hoist this quarter's A-fragments into registers (frees wlds)
    HU a[9];
#pragma unroll
    for (int rs = 0; rs < 9; ++rs)
      a[rs].u = *(const uint4*)&wlds[(rs * 2 + mt) * 512 + lane * 8];
    // (2) all waves must own their A before wlds is overwritten
    __syncthreads();

    float xf0[8], xf1[8];
    if (cq < 3) {
      // (3) async w-DMA for next quarter (overlaps K-loop)
#pragma unroll
      for (int s = 0; s < 3; ++s) {
        int f = s * 8 + wave;
        if (f < 18) {
          int gf = (f >> 1) * 8 + (cq + 1) * 2 + (f & 1);
          gload_lds16(&wbuf[(gf * 64 + lane) * 8], &wlds[f * 512]);
        }
      }
      // (4) issue next x-tile loads into registers (issue-early)
      {
        int id = wave;  // task 0: rows 0..1
        int row = id >> 2, cblk = (id >> 1) & 1, w2 = id & 1;
        int hin = h - 1 + row;
        const float* base =
            x + (((size_t)(nb * 64 + (cq + 1) * 16 + cblk * 8) * 128 + hin) * 128);
        int w = w2 * 64 + lane;
        if (hin >= 0 && hin < 128) {
#pragma unroll
          for (int j = 0; j < 8; ++j) xf0[j] = base[(size_t)j * 16384 + w];
        }
      }
      if (wave < 4) {
        int id = 8 + wave;  // task 1: row 2
        int cblk = (id >> 1) & 1, w2 = id & 1;
        int hin = h + 1;
        const float* base =
            x + (((size_t)(nb * 64 + (cq + 1) * 16 + cblk * 8) * 128 + hin) * 128);
        int w = w2 * 64 + lane;
        if (hin < 128) {
#pragma unroll
          for (int j = 0; j < 8; ++j) xf1[j] = base[(size_t)j * 16384 + w];
        }
      }
    }

    // (5) K-loop: pure {ds_read B, MFMA}
#pragma unroll
    for (int r = 0; r < 3; ++r) {
#pragma unroll
      for (int s = 0; s < 3; ++s) {
        int rs = r * 3 + s;
        int ps = nq * 32 + l31 + s;  // halo-indexed pixel slot
        HU b;
        b.u = *(const uint4*)&xlds[cur][((r * 2 + half) * 130 + ps) * 8];
        acc = __builtin_amdgcn_mfma_f32_32x32x16_f16(a[rs].h, b.h, acc, 0, 0, 0);
      }
    }

    // (6) write-late: convert + store next x-tile into the other buffer
    if (cq < 3) {
      {
        int id = wave;
        int row = id >> 2, cblk = (id >> 1) & 1, w2 = id & 1;
        int hin = h - 1 + row;
        int w = w2 * 64 + lane;
        uint4 v = make_uint4(0u, 0u, 0u, 0u);
        if (hin >= 0 && hin < 128) {
          PK p0, p1, p2, p3;
          p0.h = __builtin_amdgcn_cvt_pkrtz(xf0[0], xf0[1]);
          p1.h = __builtin_amdgcn_cvt_pkrtz(xf0[2], xf0[3]);
          p2.h = __builtin_amdgcn_cvt_pkrtz(xf0[4], xf0[5]);
          p3.h = __builtin_amdgcn_cvt_pkrtz(xf0[6], xf0[7]);
          v = make_uint4(p0.u, p1.u, p2.u, p3.u);
        }
        *(uint4*)&xlds[cur ^ 1][((row * 2 + cblk) * 130 + 1 + w) * 8] = v;
      }
      if (wave < 4) {
        int id = 8 + wave;
        int cblk = (id >> 1) & 1, w2 = id & 1;
        int hin = h + 1;
        int w = w2 * 64 + lane;
        uint4 v = make_uint4(0u, 0u, 0u, 0u);
        if (hin < 128) {
          PK p0, p1, p2, p3;
          p0.h = __builtin_amdgcn_cvt_pkrtz(xf1[0], xf1[1]);
          p1.h = __builtin_amdgcn_cvt_pkrtz(xf1[2], xf1[3]);
          p2.h = __builtin_amdgcn_cvt_pkrtz(xf1[4], xf1[5]);
          p3.h = __builtin_amdgcn_cvt_pkrtz(xf1[6], xf1[7]);
          v = make_uint4(p0.u, p1.u, p2.u, p3.u);
        }
        *(uint4*)&xlds[cur ^ 1][((2 * 2 + cblk) * 130 + 1 + w) * 8] = v;
      }
      // (7) next phase may read xlds[cur^1] and wlds
      __syncthreads();
    }
  }

  // ---- epilogue: C/D layout col = lane&31 (pixel), row = (reg&3)+8*(reg>>2)+4*half (o) ----
  int p = nq * 32 + l31;
  size_t outbase = (size_t)nb * 64 * 16384 + (size_t)h * 128 + p;
#pragma unroll
  for (int reg = 0; reg < 16; ++reg) {
    int o = mt * 32 + (reg & 3) + 8 * (reg >> 2) + 4 * half;
    out[outbase + (size_t)o * 16384] = acc[reg] + bias[o];
  }
}

extern "C" void kernel_launch(void* const* d_in, const int* in_sizes, int n_in,
                              void* d_out, int out_size, void* d_ws, size_t ws_size,
                              hipStream_t stream) {
  const float* x = (const float*)d_in[0];
  const float* w = (const float*)d_in[1];
  const float* b = (const float*)d_in[2];
  float* out = (float*)d_out;
  u16* wbuf = (u16*)d_ws;  // 36864 fp16 = 73728 B of scratch

  prep_w<<<dim3(144), dim3(256), 0, stream>>>(w, wbuf);
  conv_mfma<<<dim3(4096), dim3(512), 0, stream>>>(x, wbuf, b, out);
}

// Round 5
// 258.025 us; speedup vs baseline: 1.2601x; 1.2601x over previous
//
#include <hip/hip_runtime.h>

typedef unsigned short u16;
typedef unsigned int u32;
typedef _Float16 half8 __attribute__((ext_vector_type(8)));
typedef __fp16 fp16x2 __attribute__((ext_vector_type(2)));
typedef float f32x16 __attribute__((ext_vector_type(16)));

union HU { uint4 u; half8 h; };
union PK { fp16x2 h; u32 u; };

__device__ __forceinline__ u16 f2h(float f) {
  union { _Float16 h; u16 u; } c;
  c.h = (_Float16)f;
  return c.u;
}

// async global->LDS DMA, 16 B per lane (lds dest = wave-uniform base + lane*16)
typedef const __attribute__((address_space(1))) u32 gu32;
typedef __attribute__((address_space(3))) u32 lu32;
__device__ __forceinline__ void gload_lds16(const void* g, void* l) {
  __builtin_amdgcn_global_load_lds((gu32*)g, (lu32*)l, 16, 0, 0);
}

// Pack weights (O=64, I=64, 3, 3) fp32 -> fp16 in exact A-fragment order:
// wbuf[((t*2 + mt)*64 + lane)*8 + j] = w[m][c][rs]
//   m = mt*32 + (lane&31), k = t*16 + (lane>>5)*8 + j, rs = k>>6, c = k&63
// K ordering: k = rs*64 + c (rs-major, c-minor); ktile t = rs*4 + Q (Q = 16-ch quarter).
__global__ void prep_w(const float* __restrict__ w, u16* __restrict__ wbuf) {
  int idx = blockIdx.x * 256 + threadIdx.x;  // 36864 total
  int j    = idx & 7;
  int lane = (idx >> 3) & 63;
  int mt   = (idx >> 9) & 1;
  int t    = idx >> 10;
  int m  = mt * 32 + (lane & 31);
  int k  = t * 16 + (lane >> 5) * 8 + j;
  int rs = k >> 6;
  int c  = k & 63;
  wbuf[idx] = f2h(w[(m * 64 + c) * 9 + rs]);
}

// Implicit-GEMM conv: M = O = 64, N = pixels, K = 576.
// v5 schedule (lessons: r1/r4 = register x-prefetch spills; r3 = weights must
// be in LDS; v3 residual = tiny staging bursts + 8 drain barriers + 2.0
// LDS-reads/MFMA):
//  * Block = 2 output rows x 128 px x 64 o (2048 blocks). 8 waves =
//    (rw, mt, np); each wave TWO 32-px ntiles sharing the A-fragment ->
//    per ktile {1 A + 2 B ds_reads, 2 MFMA} = 1.5 LDS-reads/MFMA.
//    acc = 2 x f32x16 = 32 regs.
//  * x staged per 32-ch HALF (2 phases): 32 tasks/phase -> 4 tasks = 32
//    independent global loads per wave issued back-to-back (v3: 12) ->
//    staging at BW, not latency.
//  * weights DMA'd (global_load_lds, no VGPR round-trip) per 16-ch quarter
//    into a DOUBLE-buffered wlds; next quarter's DMA issues before the
//    current K-loop -> w-latency hidden under MFMA. 6 barriers total.
//  * NOTHING held in registers across a K-loop -> no spill (launch_bounds
//    (512,4) gives a 128-reg budget; need ~90).
// LDS: xlds [row4][cblk4][slot130][ch8] = 33,280 B + wlds 2 x 18,432 B
//   -> 70,144 B -> 2 blocks/CU (16 waves, 50% cap; cross-block overlap
//   covers the two serial x-stage windows).
// Halo-padded pixel axis (slots 0/129 zeroed once) -> no bounds logic in
// K-loop. All LDS ops lane-contiguous 16 B -> conflict-free.
// XCD swizzle: 2048 % 8 == 0; wg = (bid&7)*256 + bid>>3 -> each XCD gets
// contiguous (nb, hg) -> neighboring blocks share input rows in its L2.
__global__ __launch_bounds__(512, 4) void conv_mfma(
    const float* __restrict__ x, const u16* __restrict__ wbuf,
    const float* __restrict__ bias, float* __restrict__ out) {
  __shared__ u16 xlds[16 * 130 * 8];   // 33,280 B
  __shared__ u16 wlds[2][18 * 512];    // 2 x 18,432 B

  int tid = threadIdx.x;
  int lane = tid & 63;
  int wave = tid >> 6;  // 0..7
  int bid = blockIdx.x;
  int wg = ((bid & 7) << 8) | (bid >> 3);  // bijective XCD-contiguous remap
  int nb = wg >> 6;        // batch [0,32)
  int hg = wg & 63;        // row-group [0,64)
  int h0 = hg * 2;

  int l31 = lane & 31;
  int half = lane >> 5;
  int rw = wave >> 2;        // output row within block (0..1)
  int mt = (wave >> 1) & 1;  // this wave's mtile
  int np = wave & 1;         // ntile pair: pixels np*64 + {0,32} + l31

  // zero halo slots (0 and 129) of all 16 slabs, once; staging writes only
  // slots 1..128, so these stay zero across both kh phases.
  if (tid < 16) {
    *(uint4*)&xlds[(tid * 130 + 0) * 8]   = make_uint4(0u, 0u, 0u, 0u);
    *(uint4*)&xlds[(tid * 130 + 129) * 8] = make_uint4(0u, 0u, 0u, 0u);
  }

  f32x16 acc[2] = {};  // [ntile within pair]

  // stage x channels kh*32..+31 for input rows h0-1..h0+2 -> xlds.
  // 32 tasks = (row4, cblk4, whalf2); each wave 4 -> 32 global loads in flight.
  auto stage_x = [&](int kh) {
#pragma unroll
    for (int s4 = 0; s4 < 4; ++s4) {
      int id = s4 * 8 + wave;     // 0..31
      int row = id >> 3;          // 0..3
      int cblk = (id >> 1) & 3;   // 0..3 (local)
      int wh = id & 1;
      int hin = h0 - 1 + row;
      int c0 = kh * 32 + cblk * 8;
      const float* base = x + (((size_t)(nb * 64 + c0) * 128 + hin) * 128);
      int wp = wh * 64 + lane;
      uint4 v = make_uint4(0u, 0u, 0u, 0u);
      if (hin >= 0 && hin < 128) {
        float f[8];
#pragma unroll
        for (int j = 0; j < 8; ++j) f[j] = base[(size_t)j * 16384 + wp];
        PK p0, p1, p2, p3;
        p0.h = __builtin_amdgcn_cvt_pkrtz(f[0], f[1]);
        p1.h = __builtin_amdgcn_cvt_pkrtz(f[2], f[3]);
        p2.h = __builtin_amdgcn_cvt_pkrtz(f[4], f[5]);
        p3.h = __builtin_amdgcn_cvt_pkrtz(f[6], f[7]);
        v = make_uint4(p0.u, p1.u, p2.u, p3.u);
      }
      *(uint4*)&xlds[((row * 4 + cblk) * 130 + 1 + wp) * 8] = v;
    }
  };

  // async-DMA quarter Q's 18 A-fragments (rs9 x mt2, 1 KB each) into wl.
  auto dma_w = [&](int Q, u16* wl) {
#pragma unroll
    for (int s3 = 0; s3 < 3; ++s3) {
      int f = s3 * 8 + wave;  // 0..17 valid
      if (f < 18) {
        int gf = (f >> 1) * 8 + Q * 2 + (f & 1);  // wbuf frag (rs*4+Q)*2+mt
        gload_lds16(&wbuf[gf * 512 + lane * 8], &wl[f * 512]);
      }
    }
  };

  // 9 ktiles of quarter (local q in half): pure {1 A + 2 B ds_read, 2 MFMA}.
  auto kloop = [&](int q, const u16* wl) {
#pragma unroll
    for (int r = 0; r < 3; ++r) {
      int row = rw + r;           // staged row index
      int cb = q * 2 + half;      // local cblk for this lane-half
      int sb = (row * 4 + cb) * 130;
#pragma unroll
      for (int s = 0; s < 3; ++s) {
        int rs = r * 3 + s;
        int ps = np * 64 + l31 + s;  // halo slot of ntile 0; ntile 1 at +32
        HU a, b0, b1;
        a.u  = *(const uint4*)&wl[(rs * 2 + mt) * 512 + lane * 8];
        b0.u = *(const uint4*)&xlds[(sb + ps) * 8];
        b1.u = *(const uint4*)&xlds[(sb + ps + 32) * 8];
        acc[0] = __builtin_amdgcn_mfma_f32_32x32x16_f16(a.h, b0.h, acc[0], 0, 0, 0);
        acc[1] = __builtin_amdgcn_mfma_f32_32x32x16_f16(a.h, b1.h, acc[1], 0, 0, 0);
      }
    }
  };

  // ---- schedule: 2 x-halves x 2 w-quarters, w double-buffered ----
  stage_x(0);
  dma_w(0, wlds[0]);
  __syncthreads();              // x(kh0) + w(Q0) ready
  dma_w(1, wlds[1]);            // in flight under K-loop
  kloop(0, wlds[0]);
  __syncthreads();              // w(Q1) ready, K(Q0) done
  kloop(1, wlds[1]);
  __syncthreads();              // K(Q1) done -> xlds & wlds[0] free
  stage_x(1);
  dma_w(2, wlds[0]);
  __syncthreads();              // x(kh1) + w(Q2) ready
  dma_w(3, wlds[1]);
  kloop(0, wlds[0]);
  __syncthreads();              // w(Q3) ready, K(Q2) done
  kloop(1, wlds[1]);

  // ---- epilogue: C/D layout col = lane&31 (pixel), row = (reg&3)+8*(reg>>2)+4*half (o) ----
  int h = h0 + rw;
#pragma unroll
  for (int i = 0; i < 2; ++i) {
    int p = np * 64 + i * 32 + l31;
    size_t ob = (size_t)nb * 64 * 16384 + (size_t)h * 128 + p;
#pragma unroll
    for (int reg = 0; reg < 16; ++reg) {
      int o = mt * 32 + (reg & 3) + 8 * (reg >> 2) + 4 * half;
      out[ob + (size_t)o * 16384] = acc[i][reg] + bias[o];
    }
  }
}

extern "C" void kernel_launch(void* const* d_in, const int* in_sizes, int n_in,
                              void* d_out, int out_size, void* d_ws, size_t ws_size,
                              hipStream_t stream) {
  const float* x = (const float*)d_in[0];
  const float* w = (const float*)d_in[1];
  const float* b = (const float*)d_in[2];
  float* out = (float*)d_out;
  u16* wbuf = (u16*)d_ws;  // 36864 fp16 = 73728 B of scratch

  prep_w<<<dim3(144), dim3(256), 0, stream>>>(w, wbuf);
  conv_mfma<<<dim3(2048), dim3(512), 0, stream>>>(x, wbuf, b, out);
}

// Round 6
// 255.952 us; speedup vs baseline: 1.2703x; 1.0081x over previous
//
#include <hip/hip_runtime.h>

typedef unsigned short u16;
typedef unsigned int u32;
typedef _Float16 half8 __attribute__((ext_vector_type(8)));
typedef __fp16 fp16x2 __attribute__((ext_vector_type(2)));
typedef float f32x16 __attribute__((ext_vector_type(16)));

union HU { uint4 u; half8 h; };
union PK { fp16x2 h; u32 u; };

__device__ __forceinline__ u16 f2h(float f) {
  union { _Float16 h; u16 u; } c;
  c.h = (_Float16)f;
  return c.u;
}

// async global->LDS DMA, 16 B per lane (lds dest = wave-uniform base + lane*16)
typedef const __attribute__((address_space(1))) u32 gu32;
typedef __attribute__((address_space(3))) u32 lu32;
__device__ __forceinline__ void gload_lds16(const void* g, void* l) {
  __builtin_amdgcn_global_load_lds((gu32*)g, (lu32*)l, 16, 0, 0);
}

// Pack weights (O=64, I=64, 3, 3) fp32 -> fp16 in exact A-fragment order:
// wbuf[((t*2 + mt)*64 + lane)*8 + j] = w[m][c][rs]
//   m = mt*32 + (lane&31), k = t*16 + (lane>>5)*8 + j, rs = k>>6, c = k&63
// K ordering: k = rs*64 + c (rs-major, c-minor); ktile t = rs*4 + Q (16-ch quarter).
__global__ void prep_w(const float* __restrict__ w, u16* __restrict__ wbuf) {
  int idx = blockIdx.x * 256 + threadIdx.x;  // 36864 total
  int j    = idx & 7;
  int lane = (idx >> 3) & 63;
  int mt   = (idx >> 9) & 1;
  int t    = idx >> 10;
  int m  = mt * 32 + (lane & 31);
  int k  = t * 16 + (lane >> 5) * 8 + j;
  int rs = k >> 6;
  int c  = k & 63;
  wbuf[idx] = f2h(w[(m * 64 + c) * 9 + rs]);
}

// Implicit-GEMM conv: M = O = 64, N = pixels, K = 576.
// v6: LDS-read-pipe optimization. v5 measured 71% LDS-pipe busy (108
// ds_read_b128/wave = 1.5 reads/MFMA) vs ~8% matrix pipe — LDS BW bound.
// New wave shape: (rw, np) computes BOTH mtiles x 2 ntiles (64o x 64px):
//   per ktile {2 A + 2 B ds_reads -> 4 MFMAs} = 1.0 reads/MFMA (-33% LDS).
//   acc = 4 x f32x16 = 64 VGPRs; launch_bounds(512,4) = 128-reg budget;
//   NOTHING held in regs across a K-loop (r1/r4 spill lesson).
// Block = 4 output rows x 128 px x 64 o; 8 waves = (rw4, np2); grid 1024.
// x staged per 16-ch QUARTER: [row6][cblk2][slot130][ch8] = 24,960 B,
//   single-buffered; 24 tasks = 3/wave, each 8 coalesced dword loads + pkrtz.
// w per quarter via global_load_lds DMA, double-buffered (2 x 18,432 B);
//   next quarter's DMA issues before the current K-loop -> hidden under MFMA.
// LDS total 61,824 B -> 2 blocks/CU (16 waves, 50% cap; cross-block overlap
//   covers the 4 serial x-stage windows).
// Halo-padded pixel axis (slots 0/129 zeroed once) -> no bounds logic.
// All LDS ops lane-contiguous 16 B -> conflict-free.
// XCD swizzle: 1024 % 8 == 0; wg = (bid&7)*128 + bid>>3.
__global__ __launch_bounds__(512, 4) void conv_mfma(
    const float* __restrict__ x, const u16* __restrict__ wbuf,
    const float* __restrict__ bias, float* __restrict__ out) {
  __shared__ u16 xlds[12 * 130 * 8];   // 24,960 B
  __shared__ u16 wlds[2][18 * 512];    // 2 x 18,432 B

  int tid = threadIdx.x;
  int lane = tid & 63;
  int wave = tid >> 6;  // 0..7
  int bid = blockIdx.x;
  int wg = ((bid & 7) << 7) | (bid >> 3);  // bijective XCD-contiguous remap
  int nb = wg >> 5;        // batch [0,32)
  int hg = wg & 31;        // row-group [0,32)
  int h0 = hg * 4;

  int l31 = lane & 31;
  int half = lane >> 5;
  int rw = wave >> 1;   // output row within block (0..3)
  int np = wave & 1;    // ntile pair: pixels np*64 + {0,32} + l31

  // zero halo slots (0 and 129) of all 12 slabs, once; staging writes only
  // slots 1..128, so these stay zero across all 4 quarters.
  if (tid < 24) {
    int sl = tid >> 1, e = tid & 1;
    *(uint4*)&xlds[(sl * 130 + e * 129) * 8] = make_uint4(0u, 0u, 0u, 0u);
  }

  f32x16 acc[2][2] = {};  // [mt][ntile]

  // stage x channels Q*16..+15 for input rows h0-1..h0+4 -> xlds.
  // 24 tasks = (row6, cblk2, whalf2); each wave 3.
  auto stage_x = [&](int Q) {
#pragma unroll
    for (int s3 = 0; s3 < 3; ++s3) {
      int id = s3 * 8 + wave;     // 0..23
      int row = id >> 2;          // 0..5
      int cblk = (id >> 1) & 1;
      int wh = id & 1;
      int hin = h0 - 1 + row;
      int c0 = Q * 16 + cblk * 8;
      const float* base = x + (((size_t)(nb * 64 + c0) * 128 + hin) * 128);
      int wp = wh * 64 + lane;
      uint4 v = make_uint4(0u, 0u, 0u, 0u);
      if (hin >= 0 && hin < 128) {
        float f[8];
#pragma unroll
        for (int j = 0; j < 8; ++j) f[j] = base[(size_t)j * 16384 + wp];
        PK p0, p1, p2, p3;
        p0.h = __builtin_amdgcn_cvt_pkrtz(f[0], f[1]);
        p1.h = __builtin_amdgcn_cvt_pkrtz(f[2], f[3]);
        p2.h = __builtin_amdgcn_cvt_pkrtz(f[4], f[5]);
        p3.h = __builtin_amdgcn_cvt_pkrtz(f[6], f[7]);
        v = make_uint4(p0.u, p1.u, p2.u, p3.u);
      }
      *(uint4*)&xlds[((row * 2 + cblk) * 130 + 1 + wp) * 8] = v;
    }
  };

  // async-DMA quarter Q's 18 A-fragments (rs9 x mt2, 1 KB each) into wl.
  auto dma_w = [&](int Q, u16* wl) {
#pragma unroll
    for (int s3 = 0; s3 < 3; ++s3) {
      int f = s3 * 8 + wave;  // 0..17 valid
      if (f < 18) {
        int gf = (f >> 1) * 8 + Q * 2 + (f & 1);  // wbuf frag (rs*4+Q)*2+mt
        gload_lds16(&wbuf[gf * 512 + lane * 8], &wl[f * 512]);
      }
    }
  };

  // 9 ktiles: per ktile {2 A + 2 B ds_read, 4 MFMA} = 1.0 reads/MFMA.
  auto kloop = [&](const u16* wl) {
#pragma unroll
    for (int r = 0; r < 3; ++r) {
      int row = rw + r;                 // staged row index 0..5
      int sb = (row * 2 + half) * 130;  // lane-half picks the quarter's cblk
#pragma unroll
      for (int s = 0; s < 3; ++s) {
        int rs = r * 3 + s;
        int ps = np * 64 + l31 + s;  // halo slot of ntile 0; ntile 1 at +32
        HU a0, a1, b0, b1;
        a0.u = *(const uint4*)&wl[(rs * 2 + 0) * 512 + lane * 8];
        a1.u = *(const uint4*)&wl[(rs * 2 + 1) * 512 + lane * 8];
        b0.u = *(const uint4*)&xlds[(sb + ps) * 8];
        b1.u = *(const uint4*)&xlds[(sb + ps + 32) * 8];
        acc[0][0] = __builtin_amdgcn_mfma_f32_32x32x16_f16(a0.h, b0.h, acc[0][0], 0, 0, 0);
        acc[0][1] = __builtin_amdgcn_mfma_f32_32x32x16_f16(a0.h, b1.h, acc[0][1], 0, 0, 0);
        acc[1][0] = __builtin_amdgcn_mfma_f32_32x32x16_f16(a1.h, b0.h, acc[1][0], 0, 0, 0);
        acc[1][1] = __builtin_amdgcn_mfma_f32_32x32x16_f16(a1.h, b1.h, acc[1][1], 0, 0, 0);
      }
    }
  };

  // ---- schedule: 4 quarters; w double-buffered (DMA hidden under kloop),
  //      x single-buffered (stage windows covered by the co-resident block) ----
  stage_x(0);
  dma_w(0, wlds[0]);
  __syncthreads();              // x(0) + w(0) ready
  dma_w(1, wlds[1]);            // in flight under kloop(0)
  kloop(wlds[0]);
  __syncthreads();              // w(1) ready, kloop(0) done -> xlds free
  stage_x(1);
  __syncthreads();              // x(1) ready
  dma_w(2, wlds[0]);            // wlds[0] free since kloop(0)
  kloop(wlds[1]);
  __syncthreads();              // w(2) ready, kloop(1) done
  stage_x(2);
  __syncthreads();              // x(2) ready
  dma_w(3, wlds[1]);
  kloop(wlds[0]);
  __syncthreads();              // w(3) ready, kloop(2) done
  stage_x(3);
  __syncthreads();              // x(3) ready
  kloop(wlds[1]);

  // ---- epilogue: C/D layout col = lane&31 (pixel), row = (reg&3)+8*(reg>>2)+4*half (o) ----
  int h = h0 + rw;
#pragma unroll
  for (int mt = 0; mt < 2; ++mt) {
#pragma unroll
    for (int i = 0; i < 2; ++i) {
      int p = np * 64 + i * 32 + l31;
      size_t ob = (size_t)nb * 64 * 16384 + (size_t)h * 128 + p;
#pragma unroll
      for (int reg = 0; reg < 16; ++reg) {
        int o = mt * 32 + (reg & 3) + 8 * (reg >> 2) + 4 * half;
        out[ob + (size_t)o * 16384] = acc[mt][i][reg] + bias[o];
      }
    }
  }
}

extern "C" void kernel_launch(void* const* d_in, const int* in_sizes, int n_in,
                              void* d_out, int out_size, void* d_ws, size_t ws_size,
                              hipStream_t stream) {
  const float* x = (const float*)d_in[0];
  const float* w = (const float*)d_in[1];
  const float* b = (const float*)d_in[2];
  float* out = (float*)d_out;
  u16* wbuf = (u16*)d_ws;  // 36864 fp16 = 73728 B of scratch

  prep_w<<<dim3(144), dim3(256), 0, stream>>>(w, wbuf);
  conv_mfma<<<dim3(1024), dim3(512), 0, stream>>>(x, wbuf, b, out);
}